// Round 1
// baseline (806.217 us; speedup 1.0000x reference)
//
#include <hip/hip_runtime.h>
#include <math.h>

#define NRES 64
#define NM   50
#define NB   128
#define NL   3
#define NCLS 10

// ---- constants (double, folded at compile time) ----
#define PI_D        3.14159265358979323846264338327950288
#define TWO_PI_D    6.28318530717958647692528676655900577
#define INV_2PI_D   0.159154943091895335768883763372514362
#define LAMBDA_D    5.32e-07
#define DIST_D      0.035
#define PLD_D       (PI_D * LAMBDA_D * DIST_D)          // pi*lambda*D
#define KD_D        (TWO_PI_D / LAMBDA_D * DIST_D)      // k*D

// LDS XOR swizzle: element (r,c) lives at r*64 + (c ^ swz(r)); gives 2-way
// (free) bank access for both the strided row reads and transposed writes.
__device__ __forceinline__ int swz(int r) {
    return ((r & 15) << 2) ^ ((r >> 4) << 4);
}

// quad_perm DPP cross-lane (lanes within a quad): xor1 = [1,0,3,2] = 0xB1,
// xor2 = [2,3,0,1] = 0x4E.
__device__ __forceinline__ float dppx1(float v) {
    return __int_as_float(__builtin_amdgcn_mov_dpp(__float_as_int(v), 0xB1, 0xF, 0xF, true));
}
__device__ __forceinline__ float dppx2(float v) {
    return __int_as_float(__builtin_amdgcn_mov_dpp(__float_as_int(v), 0x4E, 0xF, 0xF, true));
}

// 16-point FFT in registers, natural-order in and out. DIR=+1 fwd (e^-i), -1 inv.
template<int DIR>
__device__ __forceinline__ void fft16(float xr[16], float xi[16]) {
    constexpr float C16[8] = {1.f, 0.92387953251128674f, 0.70710678118654752f, 0.38268343236508977f,
                              0.f, -0.38268343236508977f, -0.70710678118654752f, -0.92387953251128674f};
    constexpr float S16[8] = {0.f, 0.38268343236508977f, 0.70710678118654752f, 0.92387953251128674f,
                              1.f, 0.92387953251128674f, 0.70710678118654752f, 0.38268343236508977f};
    constexpr int rev[16] = {0,8,4,12,2,10,6,14,1,9,5,13,3,11,7,15};
    float yr[16], yi[16];
#pragma unroll
    for (int i = 0; i < 16; i++) { yr[i] = xr[rev[i]]; yi[i] = xi[rev[i]]; }
#pragma unroll
    for (int len = 1; len < 16; len <<= 1) {
#pragma unroll
        for (int base = 0; base < 16; base += 2 * len) {
#pragma unroll
            for (int j = 0; j < len; j++) {
                const int tw = j * (8 / len);
                const float wr = C16[tw];
                const float wi = (DIR > 0) ? -S16[tw] : S16[tw];
                const int i0 = base + j, i1 = base + j + len;
                float br = yr[i1] * wr - yi[i1] * wi;
                float bi = yr[i1] * wi + yi[i1] * wr;
                float ar = yr[i0], ai = yi[i0];
                yr[i0] = ar + br; yi[i0] = ai + bi;
                yr[i1] = ar - br; yi[i1] = ai - bi;
            }
        }
    }
#pragma unroll
    for (int i = 0; i < 16; i++) { xr[i] = yr[i]; xi[i] = yi[i]; }
}

// One batched length-64 FFT pass over all 64 "rows" of the LDS field, with
// transposed write-back. Group g (=tid>>2) owns row g; lane t (=tid&3) holds
// samples x[4*n1+t]. Optional pre-multiply by exp(i*phase[g][c]) (layer mask)
// and post-multiply by a 64-entry table indexed by the output frequency.
template<int DIR>
__device__ __forceinline__ void fft_pass(
    float* lre, float* lim,
    const float* w64c, const float* w64s,
    int g, int t,
    const float* __restrict__ phasemask,   // null or [4096] row-major
    const float* postr, const float* posti, // null or [64] (LDS)
    float scale)
{
    float xr[16], xi[16];
#pragma unroll
    for (int j = 0; j < 16; j++) {
        int c = 4 * j + t;
        int a = g * 64 + (c ^ swz(g));
        xr[j] = lre[a]; xi[j] = lim[a];
    }
    if (phasemask) {
#pragma unroll
        for (int j = 0; j < 16; j++) {
            float ph = phasemask[g * 64 + 4 * j + t];
            float s, c;
            sincosf(ph, &s, &c);
            float rr = xr[j] * c - xi[j] * s;
            xi[j] = xr[j] * s + xi[j] * c;
            xr[j] = rr;
        }
    }
    fft16<DIR>(xr, xi);
    // twiddle W64^{t*k1}
#pragma unroll
    for (int k = 0; k < 16; k++) {
        int idx = t * k;  // <= 45
        float wr = w64c[idx];
        float wi = (DIR > 0) ? -w64s[idx] : w64s[idx];
        float rr = xr[k] * wr - xi[k] * wi;
        xi[k] = xr[k] * wi + xi[k] * wr;
        xr[k] = rr;
    }
    // cross-lane 4-point DFT over the quad
    const float s2 = (t & 2) ? -1.f : 1.f;
#pragma unroll
    for (int k = 0; k < 16; k++) {
        float wr = dppx2(xr[k]), wi = dppx2(xi[k]);
        xr[k] = fmaf(xr[k], s2, wr);
        xi[k] = fmaf(xi[k], s2, wi);
    }
    if (t == 3) {  // twiddle: fwd * -i, inv * +i
#pragma unroll
        for (int k = 0; k < 16; k++) {
            float tr = xr[k];
            if (DIR > 0) { xr[k] = xi[k];  xi[k] = -tr; }
            else         { xr[k] = -xi[k]; xi[k] = tr; }
        }
    }
    const float s1 = (t & 1) ? -1.f : 1.f;
#pragma unroll
    for (int k = 0; k < 16; k++) {
        float wr = dppx1(xr[k]), wi = dppx1(xi[k]);
        xr[k] = fmaf(xr[k], s1, wr);
        xi[k] = fmaf(xi[k], s1, wi);
    }
    const int sig = ((t & 1) << 1) | (t >> 1);  // lane t holds X[k1 + 16*sig]
    __syncthreads();  // all reads done before in-place transposed writes
#pragma unroll
    for (int k1 = 0; k1 < 16; k1++) {
        int kk = k1 + 16 * sig;
        float rr = xr[k1] * scale, ii = xi[k1] * scale;
        if (postr) {
            float pr = postr[kk], pi = posti[kk];
            float r2_ = rr * pr - ii * pi;
            ii = rr * pi + ii * pr;
            rr = r2_;
        }
        int a = kk * 64 + (g ^ swz(kk));  // transposed store
        lre[a] = rr; lim[a] = ii;
    }
    __syncthreads();
}

__global__ __launch_bounds__(256) void donn_main(
    const float* __restrict__ x,
    const float* __restrict__ sre,
    const float* __restrict__ sim,
    const float* __restrict__ phase,
    const float* __restrict__ fcw,
    const float* __restrict__ fcb,
    float* __restrict__ out)
{
    __shared__ float lre[4096];
    __shared__ float lim[4096];
    __shared__ float w64c[64], w64s[64];
    __shared__ float hxr[64], hxi[64], hyr[64], hyi[64];

    const int tid = threadIdx.x;
    const int bid = blockIdx.x;
    const int b = bid & (NB - 1);
    const int m = bid >> 7;

    // per-block tables (cheap, fully L1-resident math)
    if (tid < 64) {
        float ang = (float)tid * (float)(TWO_PI_D / 64.0);
        w64c[tid] = cosf(ang);
        w64s[tid] = sinf(ang);
        // fftfreq(64, 1e-6)[tid] = signed_idx * 15625.0
        double f = (double)((tid < 32) ? tid : tid - 64) * 15625.0;
        double phd = -PLD_D * f * f;                       // -pi*lambda*D*f^2
        double r1 = phd - TWO_PI_D * rint(phd * INV_2PI_D); // range-reduce in f64
        hxr[tid] = cosf((float)r1);
        hxi[tid] = sinf((float)r1);
        double phy = phd + KD_D;                            // fold e^{ikD} into Hy
        double r2 = phy - TWO_PI_D * rint(phy * INV_2PI_D);
        hyr[tid] = cosf((float)r2);
        hyi[tid] = sinf((float)r2);
    }

    // stage field = x[b] * screens[m] into swizzled LDS (coalesced reads)
    const float* xb = x + b * 4096;
    const float* sr = sre + m * 4096;
    const float* si = sim + m * 4096;
#pragma unroll
    for (int i = 0; i < 16; i++) {
        int e = i * 256 + tid;
        int r = e >> 6, c = e & 63;
        int a = r * 64 + (c ^ swz(r));
        float xv = xb[e];
        lre[a] = xv * sr[e];
        lim[a] = xv * si[e];
    }
    __syncthreads();

    const int g = tid >> 2, t = tid & 3;

#pragma unroll 1
    for (int l = 0; l < NL; l++) {
        // field *= exp(i*phase_l); F = fft2; F *= Hx[v]*Hy[u]*e^{ikD}; field = ifft2
        fft_pass< 1>(lre, lim, w64c, w64s, g, t, phase + l * 4096, hxr, hxi, 1.0f);
        fft_pass< 1>(lre, lim, w64c, w64s, g, t, nullptr,          hyr, hyi, 1.0f);
        fft_pass<-1>(lre, lim, w64c, w64s, g, t, nullptr, nullptr, nullptr, 1.0f / 64.0f);
        fft_pass<-1>(lre, lim, w64c, w64s, g, t, nullptr, nullptr, nullptr, 1.0f / 64.0f);
    }

    // intensity + fused FC (weights are L2-hot; 10 dots of 4096 per block)
    float iv[16];
#pragma unroll
    for (int i = 0; i < 16; i++) {
        int e = i * 256 + tid;
        int r = e >> 6, c = e & 63;
        int a = r * 64 + (c ^ swz(r));
        float re = lre[a], im = lim[a];
        iv[i] = re * re + im * im;
    }
    float part[NCLS];
#pragma unroll
    for (int c2 = 0; c2 < NCLS; c2++) part[c2] = 0.f;
#pragma unroll
    for (int c2 = 0; c2 < NCLS; c2++) {
        const float* wrow = fcw + c2 * 4096;
#pragma unroll
        for (int i = 0; i < 16; i++) {
            int e = i * 256 + tid;
            part[c2] = fmaf(iv[i], wrow[e], part[c2]);
        }
    }
#pragma unroll
    for (int c2 = 0; c2 < NCLS; c2++) {
        float v = part[c2];
#pragma unroll
        for (int off = 32; off >= 1; off >>= 1) v += __shfl_down(v, off);
        if ((tid & 63) == 0) atomicAdd(&out[b * NCLS + c2], v * (1.0f / (float)NM));
    }
    if (m == 0 && tid < NCLS) atomicAdd(&out[b * NCLS + tid], fcb[tid]);
}

extern "C" void kernel_launch(void* const* d_in, const int* in_sizes, int n_in,
                              void* d_out, int out_size, void* d_ws, size_t ws_size,
                              hipStream_t stream) {
    const float* x   = (const float*)d_in[0];
    const float* sre = (const float*)d_in[1];
    const float* sim = (const float*)d_in[2];
    const float* ph  = (const float*)d_in[3];
    const float* fcw = (const float*)d_in[4];
    const float* fcb = (const float*)d_in[5];
    float* out = (float*)d_out;

    hipMemsetAsync(out, 0, (size_t)(NB * NCLS) * sizeof(float), stream);
    donn_main<<<NM * NB, 256, 0, stream>>>(x, sre, sim, ph, fcw, fcb, out);
}